// Round 6
// baseline (769.060 us; speedup 1.0000x reference)
//
#include <hip/hip_runtime.h>
#include <hip/hip_bf16.h>
#include <math.h>

#define NMSG 16384
#define NNEI 10
#define INF_ 135
#define KPAD 160
#define HID 256
#define DPH 64
#define DEPTH 5

typedef __attribute__((ext_vector_type(8))) short short8b;
typedef __attribute__((ext_vector_type(4))) float f32x4;
typedef __hip_bfloat16 bf16;

__device__ __forceinline__ float sigmoidf_(float x){ return 1.f/(1.f+expf(-x)); }
__device__ __forceinline__ float b2f(unsigned short u){ return __uint_as_float(((unsigned)u)<<16); }

__device__ __forceinline__ void gload_lds16(const void* g, void* l){
    __builtin_amdgcn_global_load_lds(
        (const __attribute__((address_space(1))) unsigned int*)g,
        (__attribute__((address_space(3))) unsigned int*)l, 16, 0, 0);
}

// C = A @ B^T.  A: [M][K] bf16 row-major.  B: [N][K] bf16 row-major (weight rows).
// 128x128 tile, BK=32, 4 waves -> 64x64 per wave, mfma 16x16x32 bf16.
// EPI 0: PRE -> y<2: fused sq reduction (bias b0=bq, AL=alpha);
//               y>=2: sel=y>>1 -> {Cb0=FZ, Cb1=FR, Cb2=FH} bf16 [M][256]
// EPI 1: KV  -> y<2: fused sk reduction (bias b0=bk, AL=alpha+64);
//               y>=2: Cb0 = V bf16 [M][256]
// EPI 2: ZR  -> n<256: Cf=sigmoid(acc+E0+b0) (zb); else Cb0=bf16(sigmoid(acc+E1+b1)*SH) (rs)
// EPI 3: H   -> hn=((1-ZB)*SH+ZB*tanh(acc+E0+b0))*(m!=0); Cf=hn; Cb0=bf16(hn);
//               Snext: atomicAdd per-row sums (rowsum of new h)
template<int EPI>
__global__ __launch_bounds__(256) void mm_k(
    const bf16* __restrict__ A, const bf16* __restrict__ B, int K,
    float* __restrict__ Cf,
    bf16* __restrict__ Cb0, bf16* __restrict__ Cb1, bf16* __restrict__ Cb2,
    const bf16* __restrict__ E0, const bf16* __restrict__ E1,
    const float* __restrict__ b0, const float* __restrict__ b1,
    const float* __restrict__ SH, const float* __restrict__ ZB,
    const float* __restrict__ AL, float* __restrict__ SKout,
    float* __restrict__ Snext)
{
    constexpr int BM=128, BK=32;
    __shared__ __align__(16) unsigned short As[BM*BK];
    __shared__ __align__(16) unsigned short Bs[BM*BK];
    const int tid  = threadIdx.x;
    const int wave = tid >> 6, lane = tid & 63;
    const int bm0  = blockIdx.x * BM, bn0 = blockIdx.y * BM;
    const int wr = wave >> 1, wc = wave & 1;
    const int rA = lane >> 2, slot = lane & 3;
    const int fr = lane & 15, fs = lane >> 4;

    f32x4 acc[4][4] = {};

    for (int k0 = 0; k0 < K; k0 += BK){
        #pragma unroll
        for (int i = 0; i < 2; ++i){
            const int r0 = (wave*2 + i) * 16;
            const int r  = r0 + rA;
            const int sw = slot ^ ((r >> 1) & 3);
            gload_lds16(A + (size_t)(bm0 + r)*K + k0 + sw*8, As + r0*BK);
            gload_lds16(B + (size_t)(bn0 + r)*K + k0 + sw*8, Bs + r0*BK);
        }
        __syncthreads();
        short8b af[4], bfr[4];
        #pragma unroll
        for (int mi = 0; mi < 4; ++mi){
            const int row = wr*64 + mi*16 + fr;
            const int sw = fs ^ ((row >> 1) & 3);
            af[mi] = *(const short8b*)((const char*)As + row*64 + sw*16);
        }
        #pragma unroll
        for (int ni = 0; ni < 4; ++ni){
            const int row = wc*64 + ni*16 + fr;
            const int sw = fs ^ ((row >> 1) & 3);
            bfr[ni] = *(const short8b*)((const char*)Bs + row*64 + sw*16);
        }
        #pragma unroll
        for (int mi = 0; mi < 4; ++mi)
            #pragma unroll
            for (int ni = 0; ni < 4; ++ni)
                acc[mi][ni] = __builtin_amdgcn_mfma_f32_16x16x32_bf16(af[mi], bfr[ni], acc[mi][ni], 0, 0, 0);
        __syncthreads();
    }

    // C/D layout: col = lane&15 (fr), row = (lane>>4)*4 + t  [m89-verified]
    if constexpr (EPI == 0 || EPI == 1){
        if (blockIdx.y < 2){
            // fused score reduction: this wave's 64 cols == one head
            const int head = ((int)blockIdx.y << 1) | wc;
            #pragma unroll
            for (int mi = 0; mi < 4; ++mi){
                #pragma unroll
                for (int t = 0; t < 4; ++t){
                    float p = 0.f;
                    #pragma unroll
                    for (int ni = 0; ni < 4; ++ni){
                        const int c = ((int)blockIdx.y << 7) + wc*64 + ni*16 + fr; // 0..255
                        float x = acc[mi][ni][t] + b0[c];
                        float lr = x > 0.f ? x : 0.01f*x;
                        p = fmaf(lr, AL[head*128 + (c & 63)], p);
                    }
                    p += __shfl_xor(p, 1); p += __shfl_xor(p, 2);
                    p += __shfl_xor(p, 4); p += __shfl_xor(p, 8);
                    if (fr == 0){
                        const int m = bm0 + wr*64 + mi*16 + fs*4 + t;
                        SKout[m*4 + head] = p;
                    }
                }
            }
        } else {
            // plain bf16 writes into a [M][256] buffer
            bf16* dst;
            if constexpr (EPI == 0){
                const int sel = blockIdx.y >> 1;           // 1,2,3
                dst = (sel == 1) ? Cb0 : (sel == 2) ? Cb1 : Cb2;
            } else {
                dst = Cb0;                                  // V
            }
            const int cbase = ((int)(blockIdx.y & 1) << 7);
            #pragma unroll
            for (int mi = 0; mi < 4; ++mi)
                #pragma unroll
                for (int ni = 0; ni < 4; ++ni)
                    #pragma unroll
                    for (int t = 0; t < 4; ++t){
                        const int m = bm0 + wr*64 + mi*16 + fs*4 + t;
                        const int c = cbase + wc*64 + ni*16 + fr;
                        dst[(size_t)m*HID + c] = __float2bfloat16(acc[mi][ni][t]);
                    }
        }
    } else if constexpr (EPI == 2){
        #pragma unroll
        for (int mi = 0; mi < 4; ++mi)
            #pragma unroll
            for (int ni = 0; ni < 4; ++ni)
                #pragma unroll
                for (int t = 0; t < 4; ++t){
                    const int m = bm0 + wr*64 + mi*16 + fs*4 + t;
                    const int n = bn0 + wc*64 + ni*16 + fr;
                    const int c = n & 255;
                    const size_t off = (size_t)m*HID + c;
                    const float v = acc[mi][ni][t];
                    if (n < 256){
                        Cf[off] = sigmoidf_(v + b2f(*(const unsigned short*)&E0[off]) + b0[c]);
                    } else {
                        float r = sigmoidf_(v + b2f(*(const unsigned short*)&E1[off]) + b1[c]);
                        Cb0[off] = __float2bfloat16(r * SH[off]);
                    }
                }
    } else {
        // EPI 3: GRU update + fused rowsum for next step's mask
        #pragma unroll
        for (int mi = 0; mi < 4; ++mi){
            #pragma unroll
            for (int t = 0; t < 4; ++t){
                const int m = bm0 + wr*64 + mi*16 + fs*4 + t;
                float psum = 0.f;
                #pragma unroll
                for (int ni = 0; ni < 4; ++ni){
                    const int n = bn0 + wc*64 + ni*16 + fr;
                    const size_t off = (size_t)m*HID + n;
                    const float ph = tanhf(acc[mi][ni][t] + b2f(*(const unsigned short*)&E0[off]) + b0[n]);
                    const float z = ZB[off], sh = SH[off];
                    float hn = (1.f - z)*sh + z*ph;
                    if (m == 0) hn = 0.f;
                    Cf[off] = hn;
                    Cb0[off] = __float2bfloat16(hn);
                    psum += hn;
                }
                if (Snext){
                    psum += __shfl_xor(psum, 1); psum += __shfl_xor(psum, 2);
                    psum += __shfl_xor(psum, 4); psum += __shfl_xor(psum, 8);
                    if (fr == 0) atomicAdd(&Snext[m], psum);
                }
            }
        }
    }
}

// one segmented fp32->bf16 conversion kernel (zero-padded columns)
struct ConvSegs {
    const float* src[10];
    bf16* dst[10];
    int srcld[10], col0[10], ncols[10], dstld[10];
    int start[10];
};
__global__ __launch_bounds__(256) void convall_k(ConvSegs cs, int total){
    int i = blockIdx.x*256 + threadIdx.x;
    if (i >= total) return;
    int s = 0;
    #pragma unroll
    for (int j = 1; j < 10; ++j) if (i >= cs.start[j]) s = j;
    const int li = i - cs.start[s];
    const int ld = cs.dstld[s];
    const int r = li / ld, c = li - r*ld;
    float v = (c < cs.ncols[s]) ? cs.src[s][(size_t)r*cs.srcld[s] + cs.col0[s] + c] : 0.f;
    cs.dst[s][li] = __float2bfloat16(v);
}

// step 0: sum_h = bv exactly (h=0 -> all-masked -> uniform softmax over V rows = bv)
__global__ __launch_bounds__(256) void bcast_k(const float* __restrict__ bv,
                                               float* __restrict__ sumh,
                                               bf16* __restrict__ sumhb){
    const int i = blockIdx.x*256 + threadIdx.x;
    const float v = bv[i & 255];
    sumh[i] = v;
    sumhb[i] = __float2bfloat16(v);
}

// attention: per message n, lane handles 4 dims of one head. V bf16 [m][256]; +bv post-softmax.
__global__ __launch_bounds__(256) void attn_k(
    const int*   __restrict__ bgraph,
    const float* __restrict__ sq,
    const float* __restrict__ sk,
    const float* __restrict__ S,
    const float* __restrict__ abias,
    const bf16*  __restrict__ V,
    const float* __restrict__ bv,
    float* __restrict__ sumh, bf16* __restrict__ sumhb)
{
    const int gid  = blockIdx.x*256 + threadIdx.x;
    const int n    = gid >> 6;
    const int lane = gid & 63;
    const int head = lane >> 4;
    const float ab  = abias[head];
    const float sqv = sq[n*4 + head];
    int g[NNEI];
    #pragma unroll
    for (int j = 0; j < NNEI; ++j) g[j] = bgraph[n*NNEI + j];
    float sc[NNEI];
    float mx = -1e30f;
    #pragma unroll
    for (int j = 0; j < NNEI; ++j){
        float s = sqv + sk[g[j]*4 + head] + ab;
        if (S[g[j]] == 0.f) s = -1e18f;
        sc[j] = s;
        mx = fmaxf(mx, s);
    }
    float den = 0.f;
    #pragma unroll
    for (int j = 0; j < NNEI; ++j){ sc[j] = expf(sc[j] - mx); den += sc[j]; }
    const float inv = 1.f/den;
    float a0=0.f, a1=0.f, a2=0.f, a3=0.f;
    #pragma unroll
    for (int j = 0; j < NNEI; ++j){
        const float w = sc[j]*inv;
        const ushort4 vv = *reinterpret_cast<const ushort4*>(
            (const unsigned short*)V + (size_t)g[j]*HID + lane*4);
        a0 = fmaf(w, b2f(vv.x), a0);
        a1 = fmaf(w, b2f(vv.y), a1);
        a2 = fmaf(w, b2f(vv.z), a2);
        a3 = fmaf(w, b2f(vv.w), a3);
    }
    const float4 bvv = *reinterpret_cast<const float4*>(bv + lane*4);
    a0 += bvv.x; a1 += bvv.y; a2 += bvv.z; a3 += bvv.w;
    const size_t off = (size_t)n*HID + lane*4;
    *reinterpret_cast<float4*>(sumh + off) = make_float4(a0, a1, a2, a3);
    bf16* ob = sumhb + off;
    ob[0]=__float2bfloat16(a0); ob[1]=__float2bfloat16(a1);
    ob[2]=__float2bfloat16(a2); ob[3]=__float2bfloat16(a3);
}

extern "C" void kernel_launch(void* const* d_in, const int* in_sizes, int n_in,
                              void* d_out, int out_size, void* d_ws, size_t ws_size,
                              hipStream_t stream) {
    const float* fmess = (const float*)d_in[0];
    const int*   bgraph= (const int*  )d_in[1];
    const float* Wq    = (const float*)d_in[2];
    const float* bq    = (const float*)d_in[3];
    const float* Wk    = (const float*)d_in[4];
    const float* bk    = (const float*)d_in[5];
    const float* Wv    = (const float*)d_in[6];
    const float* bv    = (const float*)d_in[7];
    const float* alpha = (const float*)d_in[8];
    const float* abias = (const float*)d_in[9];
    const float* Wz    = (const float*)d_in[10];
    const float* bz    = (const float*)d_in[11];
    const float* Wr    = (const float*)d_in[12];
    const float* Ur    = (const float*)d_in[13];
    const float* bur   = (const float*)d_in[14];
    const float* Wh    = (const float*)d_in[15];
    const float* bh    = (const float*)d_in[16];
    float* out = (float*)d_out;

    const size_t NH = (size_t)NMSG*HID;
    char* p = (char*)d_ws;
    auto alloc = [&](size_t bytes)->char*{ char* r = p; p += (bytes + 255) & ~(size_t)255; return r; };
    bf16* fmessb = (bf16*)alloc((size_t)NMSG*KPAD*2);
    bf16* Wcat   = (bf16*)alloc((size_t)1024*KPAD*2);
    bf16* WKV    = (bf16*)alloc((size_t)512*HID*2);
    bf16* WZR    = (bf16*)alloc((size_t)512*HID*2);
    bf16* WH     = (bf16*)alloc((size_t)256*HID*2);
    bf16* FZb    = (bf16*)alloc(NH*2);
    bf16* FRb    = (bf16*)alloc(NH*2);
    bf16* FHb    = (bf16*)alloc(NH*2);
    bf16* Vb     = (bf16*)alloc(NH*2);
    // contiguous zero region: h | hb | S_all[5]
    char* zreg   = alloc(NH*4 + NH*2 + 5*(size_t)NMSG*4);
    float* h     = (float*)zreg;
    bf16*  hb    = (bf16*)(zreg + NH*4);
    float* S_all = (float*)(zreg + NH*4 + NH*2);
    const size_t zbytes = NH*4 + NH*2 + 5*(size_t)NMSG*4;
    float* sumh  = (float*)alloc(NH*4);
    bf16* sumhb  = (bf16*)alloc(NH*2);
    bf16* rsb    = (bf16*)alloc(NH*2);
    float* zb    = (float*)alloc(NH*4);
    float* sq    = (float*)alloc((size_t)NMSG*4*4);
    float* sk    = (float*)alloc((size_t)NMSG*4*4);

    const dim3 gb(256);
    const int rgrid = NMSG*64/256;

    // ---- single segmented conversion kernel ----
    {
        ConvSegs cs;
        const size_t WQK = (size_t)256*KPAD;
        const float* srcs[10] = {fmess, Wq, Wz, Wr, Wh, Wk, Wv, Wz, Ur, Wh};
        bf16* dsts[10] = {fmessb, Wcat, Wcat+WQK, Wcat+2*WQK, Wcat+3*WQK,
                          WKV, WKV+(size_t)256*HID, WZR, WZR+(size_t)256*HID, WH};
        int srclds[10] = {INF_, INF_, INF_+HID, INF_, INF_+HID, HID, HID, INF_+HID, HID, INF_+HID};
        int col0s[10]  = {0,0,0,0,0, 0,0,INF_,0,INF_};
        int ncolss[10] = {INF_,INF_,INF_,INF_,INF_, HID,HID,HID,HID,HID};
        int dstlds[10] = {KPAD,KPAD,KPAD,KPAD,KPAD, HID,HID,HID,HID,HID};
        int sizes[10]  = {NMSG*KPAD, 256*KPAD,256*KPAD,256*KPAD,256*KPAD,
                          256*HID,256*HID,256*HID,256*HID,256*HID};
        int st = 0;
        for (int j = 0; j < 10; ++j){
            cs.src[j]=srcs[j]; cs.dst[j]=dsts[j]; cs.srcld[j]=srclds[j];
            cs.col0[j]=col0s[j]; cs.ncols[j]=ncolss[j]; cs.dstld[j]=dstlds[j];
            cs.start[j]=st; st += sizes[j];
        }
        convall_k<<<(st+255)/256, gb, 0, stream>>>(cs, st);
    }
    hipMemsetAsync(zreg, 0, zbytes, stream);

    // ---- precompute: [sq | Fz | Fr | Fh] from fmess_bf16 @ Wcat^T (K=160) ----
    mm_k<0><<<dim3(NMSG/128, 8), gb, 0, stream>>>(fmessb, Wcat, KPAD,
        nullptr, FZb, FRb, FHb, nullptr, nullptr, bq, nullptr, nullptr, nullptr,
        alpha, sq, nullptr);

    // ---- step 0 (h=0): sum_h = bv exactly ----
    bcast_k<<<NH/256, gb, 0, stream>>>(bv, sumh, sumhb);
    mm_k<2><<<dim3(NMSG/128, 4), gb, 0, stream>>>(sumhb, WZR, HID,
        zb, rsb, nullptr, nullptr, FZb, FRb, bz, bur, sumh, nullptr,
        nullptr, nullptr, nullptr);
    mm_k<3><<<dim3(NMSG/128, 2), gb, 0, stream>>>(rsb, WH, HID,
        h, hb, nullptr, nullptr, FHb, nullptr, bh, nullptr, sumh, zb,
        nullptr, nullptr, S_all + 1*NMSG);

    // ---- steps 1..4 ----
    for (int step = 1; step < DEPTH; ++step){
        float* hout = (step == DEPTH-1) ? out : h;
        float* Snext = (step < DEPTH-1) ? (S_all + (step+1)*(size_t)NMSG) : nullptr;
        // KV GEMM: y<2 -> fused sk; y>=2 -> V bf16
        mm_k<1><<<dim3(NMSG/128, 4), gb, 0, stream>>>(hb, WKV, HID,
            nullptr, Vb, nullptr, nullptr, nullptr, nullptr, bk, nullptr, nullptr, nullptr,
            alpha + DPH, sk, nullptr);
        attn_k<<<rgrid, gb, 0, stream>>>(bgraph, sq, sk, S_all + step*(size_t)NMSG,
                                         abias, Vb, bv, sumh, sumhb);
        mm_k<2><<<dim3(NMSG/128, 4), gb, 0, stream>>>(sumhb, WZR, HID,
            zb, rsb, nullptr, nullptr, FZb, FRb, bz, bur, sumh, nullptr,
            nullptr, nullptr, nullptr);
        mm_k<3><<<dim3(NMSG/128, 2), gb, 0, stream>>>(rsb, WH, HID,
            hout, hb, nullptr, nullptr, FHb, nullptr, bh, nullptr, sumh, zb,
            nullptr, nullptr, Snext);
    }
}

// Round 8
// 451.889 us; speedup vs baseline: 1.7019x; 1.7019x over previous
//
#include <hip/hip_runtime.h>
#include <hip/hip_bf16.h>
#include <math.h>

#define NMSG 16384
#define NNEI 10
#define INF_ 135
#define KPAD 160
#define HID 256
#define DPH 64
#define DEPTH 5

typedef __attribute__((ext_vector_type(8))) short short8b;
typedef __attribute__((ext_vector_type(4))) float f32x4;
typedef __hip_bfloat16 bf16;

__device__ __forceinline__ float sigmoidf_(float x){ return 1.f/(1.f+expf(-x)); }
__device__ __forceinline__ float b2f(unsigned short u){ return __uint_as_float(((unsigned)u)<<16); }

__device__ __forceinline__ void gload_lds16(const void* g, void* l){
    __builtin_amdgcn_global_load_lds(
        (const __attribute__((address_space(1))) unsigned int*)g,
        (__attribute__((address_space(3))) unsigned int*)l, 16, 0, 0);
}

// C = A @ B^T.  A: [M][K] bf16 row-major.  B: [N][K] bf16 row-major (weight rows).
// Tile 128x64, BK=32, 4 waves; wave w owns rows w*32..w*32+31, ALL 64 cols
// (so a score-path wave covers one full head -> in-wave shfl reduction only).
// EPI 0: PRE -> y<4: fused sq (head=y, b0=bq, AL=alpha);
//               y>=4: sel=(y-4)>>2 -> {Cb0=FZ,Cb1=FR,Cb2=FH}, cbase=((y-4)&3)*64
// EPI 1: KV  -> y<4: fused sk (head=y, b0=bk, AL=alpha+64); y>=4: Cb0=V, cbase=(y-4)*64
// EPI 2: ZR  -> y<4: Cb0=zbb=bf16(sigmoid(acc+E0+b0)); y>=4: Cb1=rsb=bf16(sigmoid(acc+E1+b1)*SH)
// EPI 3: H   -> hn=((1-ZBB)*SH+ZBB*tanh(acc+E0+b0))*(m!=0); Cf?=hn fp32; Cb0?=bf16(hn);
//               Snext?: atomicAdd partial rowsums (next step's mask)
template<int EPI>
__global__ __launch_bounds__(256) void mm_k(
    const bf16* __restrict__ A, const bf16* __restrict__ B, int K,
    float* __restrict__ Cf,
    bf16* __restrict__ Cb0, bf16* __restrict__ Cb1, bf16* __restrict__ Cb2,
    const bf16* __restrict__ E0, const bf16* __restrict__ E1,
    const float* __restrict__ b0, const float* __restrict__ b1,
    const bf16* __restrict__ SH, const bf16* __restrict__ ZBB,
    const float* __restrict__ AL, float* __restrict__ SKout,
    float* __restrict__ Snext)
{
    constexpr int BM=128, BN=64, BK=32;
    __shared__ __align__(16) unsigned short As[BM*BK];
    __shared__ __align__(16) unsigned short Bs[BN*BK];
    const int tid = threadIdx.x;
    const int w = tid >> 6, lane = tid & 63;
    const int bm0 = blockIdx.x * BM, bn0 = blockIdx.y * BN;
    const int rq = lane >> 2, slot = lane & 3;
    const int fr = lane & 15, fs = lane >> 4;

    f32x4 acc[2][4] = {};

    for (int k0 = 0; k0 < K; k0 += BK){
        #pragma unroll
        for (int i = 0; i < 2; ++i){
            const int r0 = i*64 + w*16;
            const int r  = r0 + rq;
            const int sw = slot ^ ((r >> 1) & 3);
            gload_lds16(A + (size_t)(bm0 + r)*K + k0 + sw*8, As + r0*BK);
        }
        {
            const int r0 = w*16;
            const int r  = r0 + rq;
            const int sw = slot ^ ((r >> 1) & 3);
            gload_lds16(B + (size_t)(bn0 + r)*K + k0 + sw*8, Bs + r0*BK);
        }
        __syncthreads();
        short8b af[2], bfr[4];
        #pragma unroll
        for (int mi = 0; mi < 2; ++mi){
            const int row = w*32 + mi*16 + fr;
            const int sw = fs ^ ((row >> 1) & 3);
            af[mi] = *(const short8b*)((const char*)As + row*64 + sw*16);
        }
        #pragma unroll
        for (int ni = 0; ni < 4; ++ni){
            const int row = ni*16 + fr;
            const int sw = fs ^ ((row >> 1) & 3);
            bfr[ni] = *(const short8b*)((const char*)Bs + row*64 + sw*16);
        }
        #pragma unroll
        for (int mi = 0; mi < 2; ++mi)
            #pragma unroll
            for (int ni = 0; ni < 4; ++ni)
                acc[mi][ni] = __builtin_amdgcn_mfma_f32_16x16x32_bf16(af[mi], bfr[ni], acc[mi][ni], 0, 0, 0);
        __syncthreads();
    }

    // C/D layout: col = lane&15 (fr), row = (lane>>4)*4 + t  [m89-verified]
    if constexpr (EPI == 0 || EPI == 1){
        if (blockIdx.y < 4){
            const int head = blockIdx.y;
            #pragma unroll
            for (int mi = 0; mi < 2; ++mi){
                #pragma unroll
                for (int t = 0; t < 4; ++t){
                    float p = 0.f;
                    #pragma unroll
                    for (int ni = 0; ni < 4; ++ni){
                        const int d = ni*16 + fr;          // 0..63 within head
                        float x = acc[mi][ni][t] + b0[head*64 + d];
                        float lr = x > 0.f ? x : 0.01f*x;
                        p = fmaf(lr, AL[head*128 + d], p);
                    }
                    p += __shfl_xor(p,1); p += __shfl_xor(p,2);
                    p += __shfl_xor(p,4); p += __shfl_xor(p,8);
                    if (fr == 0){
                        const int m = bm0 + w*32 + mi*16 + fs*4 + t;
                        SKout[m*4 + head] = p;
                    }
                }
            }
        } else {
            bf16* dst; int cbase;
            if constexpr (EPI == 0){
                const int sel = ((int)blockIdx.y - 4) >> 2;
                dst = (sel == 0) ? Cb0 : (sel == 1) ? Cb1 : Cb2;
                cbase = (((int)blockIdx.y - 4) & 3) * 64;
            } else {
                dst = Cb0;
                cbase = ((int)blockIdx.y - 4) * 64;
            }
            #pragma unroll
            for (int mi = 0; mi < 2; ++mi)
                #pragma unroll
                for (int ni = 0; ni < 4; ++ni)
                    #pragma unroll
                    for (int t = 0; t < 4; ++t){
                        const int m = bm0 + w*32 + mi*16 + fs*4 + t;
                        const int c = cbase + ni*16 + fr;
                        dst[(size_t)m*HID + c] = __float2bfloat16(acc[mi][ni][t]);
                    }
        }
    } else if constexpr (EPI == 2){
        const bool zpath = (blockIdx.y < 4);
        const int cbase = ((int)blockIdx.y & 3) * 64;
        #pragma unroll
        for (int mi = 0; mi < 2; ++mi)
            #pragma unroll
            for (int ni = 0; ni < 4; ++ni)
                #pragma unroll
                for (int t = 0; t < 4; ++t){
                    const int m = bm0 + w*32 + mi*16 + fs*4 + t;
                    const int c = cbase + ni*16 + fr;
                    const size_t off = (size_t)m*HID + c;
                    const float v = acc[mi][ni][t];
                    if (zpath){
                        Cb0[off] = __float2bfloat16(
                            sigmoidf_(v + b2f(*(const unsigned short*)&E0[off]) + b0[c]));
                    } else {
                        float r = sigmoidf_(v + b2f(*(const unsigned short*)&E1[off]) + b1[c]);
                        Cb1[off] = __float2bfloat16(r * b2f(*(const unsigned short*)&SH[off]));
                    }
                }
    } else {
        const int cbase = (int)blockIdx.y * 64;
        #pragma unroll
        for (int mi = 0; mi < 2; ++mi){
            #pragma unroll
            for (int t = 0; t < 4; ++t){
                const int m = bm0 + w*32 + mi*16 + fs*4 + t;
                float psum = 0.f;
                #pragma unroll
                for (int ni = 0; ni < 4; ++ni){
                    const int c = cbase + ni*16 + fr;
                    const size_t off = (size_t)m*HID + c;
                    const float ph = tanhf(acc[mi][ni][t] + b2f(*(const unsigned short*)&E0[off]) + b0[c]);
                    const float z  = b2f(*(const unsigned short*)&ZBB[off]);
                    const float sh = b2f(*(const unsigned short*)&SH[off]);
                    float hn = (1.f - z)*sh + z*ph;
                    if (m == 0) hn = 0.f;
                    if (Cf)  Cf[off]  = hn;
                    if (Cb0) Cb0[off] = __float2bfloat16(hn);
                    psum += hn;
                }
                if (Snext){
                    psum += __shfl_xor(psum,1); psum += __shfl_xor(psum,2);
                    psum += __shfl_xor(psum,4); psum += __shfl_xor(psum,8);
                    if (fr == 0) atomicAdd(&Snext[m], psum);
                }
            }
        }
    }
}

// one segmented fp32->bf16 conversion kernel (zero-padded columns)
struct ConvSegs {
    const float* src[10];
    bf16* dst[10];
    int srcld[10], col0[10], ncols[10], dstld[10];
    int start[10];
};
__global__ __launch_bounds__(256) void convall_k(ConvSegs cs, int total){
    int i = blockIdx.x*256 + threadIdx.x;
    if (i >= total) return;
    int s = 0;
    #pragma unroll
    for (int j = 1; j < 10; ++j) if (i >= cs.start[j]) s = j;
    const int li = i - cs.start[s];
    const int ld = cs.dstld[s];
    const int r = li / ld, c = li - r*ld;
    float v = (c < cs.ncols[s]) ? cs.src[s][(size_t)r*cs.srcld[s] + cs.col0[s] + c] : 0.f;
    cs.dst[s][li] = __float2bfloat16(v);
}

// step 0: sum_h = bv exactly (h=0 -> all-masked -> uniform softmax over V rows = bv)
__global__ __launch_bounds__(256) void bcast_k(const float* __restrict__ bv,
                                               bf16* __restrict__ sumhb){
    const int i = blockIdx.x*256 + threadIdx.x;
    sumhb[i] = __float2bfloat16(bv[i & 255]);
}

// attention: per message n, lane handles 4 dims of one head. V bf16 [m][256]; +bv post-softmax.
__global__ __launch_bounds__(256) void attn_k(
    const int*   __restrict__ bgraph,
    const float* __restrict__ sq,
    const float* __restrict__ sk,
    const float* __restrict__ S,
    const float* __restrict__ abias,
    const bf16*  __restrict__ V,
    const float* __restrict__ bv,
    bf16* __restrict__ sumhb)
{
    const int gid  = blockIdx.x*256 + threadIdx.x;
    const int n    = gid >> 6;
    const int lane = gid & 63;
    const int head = lane >> 4;
    const float ab  = abias[head];
    const float sqv = sq[n*4 + head];
    int g[NNEI];
    #pragma unroll
    for (int j = 0; j < NNEI; ++j) g[j] = bgraph[n*NNEI + j];
    float sc[NNEI];
    float mx = -1e30f;
    #pragma unroll
    for (int j = 0; j < NNEI; ++j){
        float s = sqv + sk[g[j]*4 + head] + ab;
        if (S[g[j]] == 0.f) s = -1e18f;
        sc[j] = s;
        mx = fmaxf(mx, s);
    }
    float den = 0.f;
    #pragma unroll
    for (int j = 0; j < NNEI; ++j){ sc[j] = expf(sc[j] - mx); den += sc[j]; }
    const float inv = 1.f/den;
    float a0=0.f, a1=0.f, a2=0.f, a3=0.f;
    #pragma unroll
    for (int j = 0; j < NNEI; ++j){
        const float w = sc[j]*inv;
        const ushort4 vv = *reinterpret_cast<const ushort4*>(
            (const unsigned short*)V + (size_t)g[j]*HID + lane*4);
        a0 = fmaf(w, b2f(vv.x), a0);
        a1 = fmaf(w, b2f(vv.y), a1);
        a2 = fmaf(w, b2f(vv.z), a2);
        a3 = fmaf(w, b2f(vv.w), a3);
    }
    const float4 bvv = *reinterpret_cast<const float4*>(bv + lane*4);
    a0 += bvv.x; a1 += bvv.y; a2 += bvv.z; a3 += bvv.w;
    ushort4 ob;
    { bf16 t0=__float2bfloat16(a0); ob.x=*(unsigned short*)&t0; }
    { bf16 t1=__float2bfloat16(a1); ob.y=*(unsigned short*)&t1; }
    { bf16 t2=__float2bfloat16(a2); ob.z=*(unsigned short*)&t2; }
    { bf16 t3=__float2bfloat16(a3); ob.w=*(unsigned short*)&t3; }
    *reinterpret_cast<ushort4*>((unsigned short*)sumhb + (size_t)n*HID + lane*4) = ob;
}

extern "C" void kernel_launch(void* const* d_in, const int* in_sizes, int n_in,
                              void* d_out, int out_size, void* d_ws, size_t ws_size,
                              hipStream_t stream) {
    const float* fmess = (const float*)d_in[0];
    const int*   bgraph= (const int*  )d_in[1];
    const float* Wq    = (const float*)d_in[2];
    const float* bq    = (const float*)d_in[3];
    const float* Wk    = (const float*)d_in[4];
    const float* bk    = (const float*)d_in[5];
    const float* Wv    = (const float*)d_in[6];
    const float* bv    = (const float*)d_in[7];
    const float* alpha = (const float*)d_in[8];
    const float* abias = (const float*)d_in[9];
    const float* Wz    = (const float*)d_in[10];
    const float* bz    = (const float*)d_in[11];
    const float* Wr    = (const float*)d_in[12];
    const float* Ur    = (const float*)d_in[13];
    const float* bur   = (const float*)d_in[14];
    const float* Wh    = (const float*)d_in[15];
    const float* bh    = (const float*)d_in[16];
    float* out = (float*)d_out;

    const size_t NH = (size_t)NMSG*HID;
    char* p = (char*)d_ws;
    auto alloc = [&](size_t bytes)->char*{ char* r = p; p += (bytes + 255) & ~(size_t)255; return r; };
    bf16* fmessb = (bf16*)alloc((size_t)NMSG*KPAD*2);
    bf16* Wcat   = (bf16*)alloc((size_t)1024*KPAD*2);
    bf16* WKV    = (bf16*)alloc((size_t)512*HID*2);
    bf16* WZR    = (bf16*)alloc((size_t)512*HID*2);
    bf16* WH     = (bf16*)alloc((size_t)256*HID*2);
    bf16* FZb    = (bf16*)alloc(NH*2);
    bf16* FRb    = (bf16*)alloc(NH*2);
    bf16* FHb    = (bf16*)alloc(NH*2);
    bf16* Vb     = (bf16*)alloc(NH*2);
    bf16* hb     = (bf16*)alloc(NH*2);
    bf16* sumhb  = (bf16*)alloc(NH*2);
    bf16* rsb    = (bf16*)alloc(NH*2);
    bf16* zbb    = (bf16*)alloc(NH*2);
    float* S_all = (float*)alloc(5*(size_t)NMSG*4);   // must be zeroed (atomicAdd targets)
    float* sq    = (float*)alloc((size_t)NMSG*4*4);
    float* sk    = (float*)alloc((size_t)NMSG*4*4);

    const dim3 gb(256);
    const int rgrid = NMSG*64/256;

    // ---- single segmented conversion kernel ----
    {
        ConvSegs cs;
        const size_t WQK = (size_t)256*KPAD;
        const float* srcs[10] = {fmess, Wq, Wz, Wr, Wh, Wk, Wv, Wz, Ur, Wh};
        bf16* dsts[10] = {fmessb, Wcat, Wcat+WQK, Wcat+2*WQK, Wcat+3*WQK,
                          WKV, WKV+(size_t)256*HID, WZR, WZR+(size_t)256*HID, WH};
        int srclds[10] = {INF_, INF_, INF_+HID, INF_, INF_+HID, HID, HID, INF_+HID, HID, INF_+HID};
        int col0s[10]  = {0,0,0,0,0, 0,0,INF_,0,INF_};
        int ncolss[10] = {INF_,INF_,INF_,INF_,INF_, HID,HID,HID,HID,HID};
        int dstlds[10] = {KPAD,KPAD,KPAD,KPAD,KPAD, HID,HID,HID,HID,HID};
        int sizes[10]  = {NMSG*KPAD, 256*KPAD,256*KPAD,256*KPAD,256*KPAD,
                          256*HID,256*HID,256*HID,256*HID,256*HID};
        int st = 0;
        for (int j = 0; j < 10; ++j){
            cs.src[j]=srcs[j]; cs.dst[j]=dsts[j]; cs.srcld[j]=srclds[j];
            cs.col0[j]=col0s[j]; cs.ncols[j]=ncolss[j]; cs.dstld[j]=dstlds[j];
            cs.start[j]=st; st += sizes[j];
        }
        convall_k<<<(st+255)/256, gb, 0, stream>>>(cs, st);
    }
    hipMemsetAsync(S_all, 0, 5*(size_t)NMSG*4, stream);

    // ---- precompute: [sq | Fz | Fr | Fh] from fmess_bf16 @ Wcat^T (K=160) ----
    mm_k<0><<<dim3(NMSG/128, 16), gb, 0, stream>>>(fmessb, Wcat, KPAD,
        nullptr, FZb, FRb, FHb, nullptr, nullptr, bq, nullptr, nullptr, nullptr,
        alpha, sq, nullptr);

    // ---- step 0 (h=0): sum_h = bv exactly ----
    bcast_k<<<NH/256, gb, 0, stream>>>(bv, sumhb);
    mm_k<2><<<dim3(NMSG/128, 8), gb, 0, stream>>>(sumhb, WZR, HID,
        nullptr, zbb, rsb, nullptr, FZb, FRb, bz, bur, sumhb, nullptr,
        nullptr, nullptr, nullptr);
    mm_k<3><<<dim3(NMSG/128, 4), gb, 0, stream>>>(rsb, WH, HID,
        nullptr, hb, nullptr, nullptr, FHb, nullptr, bh, nullptr, sumhb, zbb,
        nullptr, nullptr, S_all + 1*(size_t)NMSG);

    // ---- steps 1..4 ----
    for (int step = 1; step < DEPTH; ++step){
        const bool last = (step == DEPTH-1);
        float* cf    = last ? out : nullptr;
        bf16*  cb    = last ? nullptr : hb;
        float* Snext = last ? nullptr : (S_all + (step+1)*(size_t)NMSG);
        mm_k<1><<<dim3(NMSG/128, 8), gb, 0, stream>>>(hb, WKV, HID,
            nullptr, Vb, nullptr, nullptr, nullptr, nullptr, bk, nullptr, nullptr, nullptr,
            alpha + DPH, sk, nullptr);
        attn_k<<<rgrid, gb, 0, stream>>>(bgraph, sq, sk, S_all + step*(size_t)NMSG,
                                         abias, Vb, bv, sumhb);
        mm_k<2><<<dim3(NMSG/128, 8), gb, 0, stream>>>(sumhb, WZR, HID,
            nullptr, zbb, rsb, nullptr, FZb, FRb, bz, bur, sumhb, nullptr,
            nullptr, nullptr, nullptr);
        mm_k<3><<<dim3(NMSG/128, 4), gb, 0, stream>>>(rsb, WH, HID,
            cf, cb, nullptr, nullptr, FHb, nullptr, bh, nullptr, sumhb, zbb,
            nullptr, nullptr, Snext);
    }
}

// Round 9
// 393.642 us; speedup vs baseline: 1.9537x; 1.1480x over previous
//
#include <hip/hip_runtime.h>
#include <hip/hip_bf16.h>
#include <math.h>

#define NMSG 16384
#define NNEI 10
#define INF_ 135
#define KPAD 160
#define HID 256
#define DPH 64
#define DEPTH 5

typedef __attribute__((ext_vector_type(8))) short short8b;
typedef __attribute__((ext_vector_type(4))) float f32x4;
typedef __hip_bfloat16 bf16;

__device__ __forceinline__ float sigmoidf_(float x){ return 1.f/(1.f+expf(-x)); }
__device__ __forceinline__ float b2f(unsigned short u){ return __uint_as_float(((unsigned)u)<<16); }
__device__ __forceinline__ float ldb(const bf16* p, size_t off){
    return b2f(*((const unsigned short*)p + off));
}

__device__ __forceinline__ void gload_lds16(const void* g, void* l){
    __builtin_amdgcn_global_load_lds(
        (const __attribute__((address_space(1))) unsigned int*)g,
        (__attribute__((address_space(3))) unsigned int*)l, 16, 0, 0);
}

// Unified GEMM kernel. C = A @ B^T per panel. A:[M][K] bf16, B:[256.. rows][K] bf16.
// EPI 0 (PRE, BM=128): y<4: fused sq (head=y, b0=bq, AL=alpha+0);
//                      y>=4: sel=(y-4)>>2 -> {Cb0=FZ,Cb1=FR,Cb2=FH}, cbase=((y-4)&3)*64
// EPI 1 (SK,  BM=64):  all blocks: head=y, fused sk (b0=bk, AL=alpha+64)
// EPI 2 (G2,  BM=64):  shared-A dual-B: acc1=A@Wv^T, acc2=A@Urv^T;
//                      sumh=acc1+b0[c]; r=sigmoid(acc2+E1+b1[c]); Cb0=bf16(sumh); Cb1=bf16(r*sumh)
// EPI 3 (G3,  BM=64):  dual-A dual-B: acc1=A1@Wh2^T, acc2=A2@Wzv^T;
//                      ph=tanh(acc1+E0+b0[c]); z=sigmoid(acc2+E1+b1[c]); sh=SH[off];
//                      hn=((1-z)sh+z·ph)·(m!=0); Cf?=hn fp32; Cb0?=bf16(hn); Snext? atomic rowsum
template<int EPI>
__global__ __launch_bounds__(256) void mm_k(
    const bf16* __restrict__ A1, const bf16* __restrict__ A2,
    const bf16* __restrict__ B1, const bf16* __restrict__ B2, int K,
    const bf16* __restrict__ E0, const bf16* __restrict__ E1,
    const float* __restrict__ b0, const float* __restrict__ b1,
    const bf16* __restrict__ SH,
    float* __restrict__ Cf, bf16* __restrict__ Cb0, bf16* __restrict__ Cb1, bf16* __restrict__ Cb2,
    const float* __restrict__ AL, float* __restrict__ SKout, float* __restrict__ Snext)
{
    constexpr int BM = (EPI==0) ? 128 : 64;
    constexpr int MF = BM/64;               // row fragments per wave
    constexpr int BK = 32;
    constexpr bool DB = (EPI>=2);
    constexpr bool DA = (EPI==3);
    __shared__ __align__(16) unsigned short As1[BM*BK];
    __shared__ __align__(16) unsigned short As2[DA ? BM*BK : 8];
    __shared__ __align__(16) unsigned short Bs1[64*BK];
    __shared__ __align__(16) unsigned short Bs2[DB ? 64*BK : 8];
    const int tid = threadIdx.x;
    const int w = tid >> 6, lane = tid & 63;
    const int bm0 = blockIdx.x * BM;
    const int bn0 = blockIdx.y * 64;
    const int rq = lane >> 2, slot = lane & 3;
    const int fr = lane & 15, fs = lane >> 4;
    const int wrow = w * (MF*16);

    f32x4 acc1[MF][4] = {};
    f32x4 acc2[MF][4] = {};

    for (int k0 = 0; k0 < K; k0 += BK){
        #pragma unroll
        for (int i = 0; i < MF; ++i){
            const int r0 = i*64 + w*16;
            const int r  = r0 + rq;
            const int sw = slot ^ ((r >> 1) & 3);
            gload_lds16(A1 + (size_t)(bm0 + r)*K + k0 + sw*8, As1 + r0*BK);
            if constexpr (DA)
                gload_lds16(A2 + (size_t)(bm0 + r)*K + k0 + sw*8, As2 + r0*BK);
        }
        {
            const int r0 = w*16;
            const int r  = r0 + rq;
            const int sw = slot ^ ((r >> 1) & 3);
            gload_lds16(B1 + (size_t)(bn0 + r)*K + k0 + sw*8, Bs1 + r0*BK);
            if constexpr (DB)
                gload_lds16(B2 + (size_t)(bn0 + r)*K + k0 + sw*8, Bs2 + r0*BK);
        }
        __syncthreads();
        short8b af1[MF], af2[MF], bv1[4], bv2[4];
        #pragma unroll
        for (int mi = 0; mi < MF; ++mi){
            const int row = wrow + mi*16 + fr;
            const int sw = fs ^ ((row >> 1) & 3);
            af1[mi] = *(const short8b*)((const char*)As1 + row*64 + sw*16);
            if constexpr (DA)
                af2[mi] = *(const short8b*)((const char*)As2 + row*64 + sw*16);
        }
        #pragma unroll
        for (int ni = 0; ni < 4; ++ni){
            const int row = ni*16 + fr;
            const int sw = fs ^ ((row >> 1) & 3);
            bv1[ni] = *(const short8b*)((const char*)Bs1 + row*64 + sw*16);
            if constexpr (DB)
                bv2[ni] = *(const short8b*)((const char*)Bs2 + row*64 + sw*16);
        }
        #pragma unroll
        for (int mi = 0; mi < MF; ++mi)
            #pragma unroll
            for (int ni = 0; ni < 4; ++ni){
                acc1[mi][ni] = __builtin_amdgcn_mfma_f32_16x16x32_bf16(af1[mi], bv1[ni], acc1[mi][ni], 0, 0, 0);
                if constexpr (DB)
                    acc2[mi][ni] = __builtin_amdgcn_mfma_f32_16x16x32_bf16(
                        DA ? af2[mi] : af1[mi], bv2[ni], acc2[mi][ni], 0, 0, 0);
            }
        __syncthreads();
    }

    // C/D layout: col = lane&15 (fr), row = (lane>>4)*4 + t  [m89-verified]
    if constexpr (EPI == 0 || EPI == 1){
        const bool score = (EPI == 1) || (blockIdx.y < 4);
        if (score){
            const int head = blockIdx.y;
            #pragma unroll
            for (int mi = 0; mi < MF; ++mi){
                #pragma unroll
                for (int t = 0; t < 4; ++t){
                    float p = 0.f;
                    #pragma unroll
                    for (int ni = 0; ni < 4; ++ni){
                        const int d = ni*16 + fr;
                        float x = acc1[mi][ni][t] + b0[head*64 + d];
                        float lr = x > 0.f ? x : 0.01f*x;
                        p = fmaf(lr, AL[head*128 + d], p);
                    }
                    p += __shfl_xor(p,1); p += __shfl_xor(p,2);
                    p += __shfl_xor(p,4); p += __shfl_xor(p,8);
                    if (fr == 0){
                        const int m = bm0 + wrow + mi*16 + fs*4 + t;
                        SKout[m*4 + head] = p;
                    }
                }
            }
        } else {
            const int sel = ((int)blockIdx.y - 4) >> 2;
            bf16* dst = (sel == 0) ? Cb0 : (sel == 1) ? Cb1 : Cb2;
            const int cbase = (((int)blockIdx.y - 4) & 3) * 64;
            #pragma unroll
            for (int mi = 0; mi < MF; ++mi)
                #pragma unroll
                for (int ni = 0; ni < 4; ++ni)
                    #pragma unroll
                    for (int t = 0; t < 4; ++t){
                        const int m = bm0 + wrow + mi*16 + fs*4 + t;
                        const int c = cbase + ni*16 + fr;
                        dst[(size_t)m*HID + c] = __float2bfloat16(acc1[mi][ni][t]);
                    }
        }
    } else if constexpr (EPI == 2){
        const int cbase = (int)blockIdx.y * 64;
        #pragma unroll
        for (int mi = 0; mi < MF; ++mi)
            #pragma unroll
            for (int ni = 0; ni < 4; ++ni)
                #pragma unroll
                for (int t = 0; t < 4; ++t){
                    const int m = bm0 + wrow + mi*16 + fs*4 + t;
                    const int c = cbase + ni*16 + fr;
                    const size_t off = (size_t)m*HID + c;
                    const float sumh = acc1[mi][ni][t] + b0[c];
                    const float r = sigmoidf_(acc2[mi][ni][t] + ldb(E1, off) + b1[c]);
                    Cb0[off] = __float2bfloat16(sumh);
                    Cb1[off] = __float2bfloat16(r * sumh);
                }
    } else {
        const int cbase = (int)blockIdx.y * 64;
        #pragma unroll
        for (int mi = 0; mi < MF; ++mi){
            #pragma unroll
            for (int t = 0; t < 4; ++t){
                const int m = bm0 + wrow + mi*16 + fs*4 + t;
                float psum = 0.f;
                #pragma unroll
                for (int ni = 0; ni < 4; ++ni){
                    const int c = cbase + ni*16 + fr;
                    const size_t off = (size_t)m*HID + c;
                    const float ph = tanhf(acc1[mi][ni][t] + ldb(E0, off) + b0[c]);
                    const float z  = sigmoidf_(acc2[mi][ni][t] + ldb(E1, off) + b1[c]);
                    const float sh = ldb(SH, off);
                    float hn = (1.f - z)*sh + z*ph;
                    if (m == 0) hn = 0.f;
                    if (Cf)  Cf[off]  = hn;
                    if (Cb0) Cb0[off] = __float2bfloat16(hn);
                    psum += hn;
                }
                if (Snext){
                    psum += __shfl_xor(psum,1); psum += __shfl_xor(psum,2);
                    psum += __shfl_xor(psum,4); psum += __shfl_xor(psum,8);
                    if (fr == 0) atomicAdd(&Snext[m], psum);
                }
            }
        }
    }
}

// segmented fp32->bf16 conversion (zero-padded columns)
struct ConvSegs {
    const float* src[8];
    bf16* dst[8];
    int srcld[8], col0[8], ncols[8], dstld[8];
    int start[8];
};
__global__ __launch_bounds__(256) void convall_k(ConvSegs cs, int total){
    int i = blockIdx.x*256 + threadIdx.x;
    if (i >= total) return;
    int s = 0;
    #pragma unroll
    for (int j = 1; j < 8; ++j) if (i >= cs.start[j]) s = j;
    const int li = i - cs.start[s];
    const int ld = cs.dstld[s];
    const int r = li / ld, c = li - r*ld;
    float v = (c < cs.ncols[s]) ? cs.src[s][(size_t)r*cs.srcld[s] + cs.col0[s] + c] : 0.f;
    cs.dst[s][li] = __float2bfloat16(v);
}

// composed weights: Urv = Ur@Wv, Wzv = Wz2@Wv (bf16); bur2 = bur + Ur@bv, bz2 = bz + Wz2@bv
__global__ __launch_bounds__(256) void wcomb_k(
    const float* __restrict__ Ur, const float* __restrict__ Wz,
    const float* __restrict__ Wv, const float* __restrict__ bv,
    const float* __restrict__ bur, const float* __restrict__ bz,
    bf16* __restrict__ Urv, bf16* __restrict__ Wzv,
    float* __restrict__ bur2, float* __restrict__ bz2)
{
    const int i = blockIdx.x, j = threadIdx.x;
    const bool zp = (i >= 256);
    const int r = zp ? i - 256 : i;
    const float* Arow = zp ? (Wz + (size_t)r*(INF_+HID) + INF_) : (Ur + (size_t)r*HID);
    float acc = 0.f;
    for (int q = 0; q < HID; ++q)
        acc = fmaf(Arow[q], Wv[(size_t)q*HID + j], acc);
    (zp ? Wzv : Urv)[(size_t)r*HID + j] = __float2bfloat16(acc);
    float part = Arow[j] * bv[j];
    part += __shfl_xor(part,1);  part += __shfl_xor(part,2);  part += __shfl_xor(part,4);
    part += __shfl_xor(part,8);  part += __shfl_xor(part,16); part += __shfl_xor(part,32);
    __shared__ float red[4];
    if ((j & 63) == 0) red[j >> 6] = part;
    __syncthreads();
    if (j == 0){
        float s = red[0] + red[1] + red[2] + red[3];
        if (zp) bz2[r] = bz[r] + s; else bur2[r] = bur[r] + s;
    }
}

// attention over h: h_agg[n] = sum_j softmax_j(score) * h[g_j]   (no bias; bv folded downstream)
__global__ __launch_bounds__(256) void attn_k(
    const int*   __restrict__ bgraph,
    const float* __restrict__ sq,
    const float* __restrict__ sk,
    const float* __restrict__ S,
    const float* __restrict__ abias,
    const bf16*  __restrict__ H,
    bf16* __restrict__ haggb)
{
    const int gid  = blockIdx.x*256 + threadIdx.x;
    const int n    = gid >> 6;
    const int lane = gid & 63;
    const int head = lane >> 4;
    const float ab  = abias[head];
    const float sqv = sq[n*4 + head];
    int g[NNEI];
    #pragma unroll
    for (int j = 0; j < NNEI; ++j) g[j] = bgraph[n*NNEI + j];
    float sc[NNEI];
    float mx = -1e30f;
    #pragma unroll
    for (int j = 0; j < NNEI; ++j){
        float s = sqv + sk[g[j]*4 + head] + ab;
        if (S[g[j]] == 0.f) s = -1e18f;
        sc[j] = s;
        mx = fmaxf(mx, s);
    }
    float den = 0.f;
    #pragma unroll
    for (int j = 0; j < NNEI; ++j){ sc[j] = expf(sc[j] - mx); den += sc[j]; }
    const float inv = 1.f/den;
    float a0=0.f, a1=0.f, a2=0.f, a3=0.f;
    #pragma unroll
    for (int j = 0; j < NNEI; ++j){
        const float w = sc[j]*inv;
        const ushort4 vv = *reinterpret_cast<const ushort4*>(
            (const unsigned short*)H + (size_t)g[j]*HID + lane*4);
        a0 = fmaf(w, b2f(vv.x), a0);
        a1 = fmaf(w, b2f(vv.y), a1);
        a2 = fmaf(w, b2f(vv.z), a2);
        a3 = fmaf(w, b2f(vv.w), a3);
    }
    ushort4 ob;
    { bf16 t0=__float2bfloat16(a0); ob.x=*(unsigned short*)&t0; }
    { bf16 t1=__float2bfloat16(a1); ob.y=*(unsigned short*)&t1; }
    { bf16 t2=__float2bfloat16(a2); ob.z=*(unsigned short*)&t2; }
    { bf16 t3=__float2bfloat16(a3); ob.w=*(unsigned short*)&t3; }
    *reinterpret_cast<ushort4*>((unsigned short*)haggb + (size_t)n*HID + lane*4) = ob;
}

extern "C" void kernel_launch(void* const* d_in, const int* in_sizes, int n_in,
                              void* d_out, int out_size, void* d_ws, size_t ws_size,
                              hipStream_t stream) {
    const float* fmess = (const float*)d_in[0];
    const int*   bgraph= (const int*  )d_in[1];
    const float* Wq    = (const float*)d_in[2];
    const float* bq    = (const float*)d_in[3];
    const float* Wk    = (const float*)d_in[4];
    const float* bk    = (const float*)d_in[5];
    const float* Wv    = (const float*)d_in[6];
    const float* bv    = (const float*)d_in[7];
    const float* alpha = (const float*)d_in[8];
    const float* abias = (const float*)d_in[9];
    const float* Wz    = (const float*)d_in[10];
    const float* bz    = (const float*)d_in[11];
    const float* Wr    = (const float*)d_in[12];
    const float* Ur    = (const float*)d_in[13];
    const float* bur   = (const float*)d_in[14];
    const float* Wh    = (const float*)d_in[15];
    const float* bh    = (const float*)d_in[16];
    float* out = (float*)d_out;

    const size_t NH = (size_t)NMSG*HID;
    char* p = (char*)d_ws;
    auto alloc = [&](size_t bytes)->char*{ char* r = p; p += (bytes + 255) & ~(size_t)255; return r; };
    bf16* fmessb = (bf16*)alloc((size_t)NMSG*KPAD*2);
    bf16* Wcat   = (bf16*)alloc((size_t)1024*KPAD*2);
    bf16* Wkb    = (bf16*)alloc((size_t)256*HID*2);
    bf16* Wvb    = (bf16*)alloc((size_t)256*HID*2);
    bf16* Wh2b   = (bf16*)alloc((size_t)256*HID*2);
    bf16* Urv    = (bf16*)alloc((size_t)256*HID*2);
    bf16* Wzv    = (bf16*)alloc((size_t)256*HID*2);
    float* bur2  = (float*)alloc(256*4);
    float* bz2   = (float*)alloc(256*4);
    bf16* FZb    = (bf16*)alloc(NH*2);
    bf16* FRb    = (bf16*)alloc(NH*2);
    bf16* FHb    = (bf16*)alloc(NH*2);
    bf16* sumhb  = (bf16*)alloc(NH*2);
    bf16* rsb    = (bf16*)alloc(NH*2);
    // contiguous zero region: hb | h_aggb | S_all[5]
    char* zreg   = alloc(NH*2 + NH*2 + 5*(size_t)NMSG*4);
    bf16*  hb    = (bf16*)zreg;
    bf16*  haggb = (bf16*)(zreg + NH*2);
    float* S_all = (float*)(zreg + NH*2 + NH*2);
    const size_t zbytes = NH*2 + NH*2 + 5*(size_t)NMSG*4;
    float* sq    = (float*)alloc((size_t)NMSG*4*4);
    float* sk    = (float*)alloc((size_t)NMSG*4*4);

    const dim3 gb(256);
    const int rgrid = NMSG*64/256;

    // ---- conversions (8 segments, one launch) ----
    {
        ConvSegs cs;
        const size_t WQK = (size_t)256*KPAD;
        const float* srcs[8] = {fmess, Wq, Wz, Wr, Wh, Wk, Wv, Wh};
        bf16* dsts[8] = {fmessb, Wcat, Wcat+WQK, Wcat+2*WQK, Wcat+3*WQK, Wkb, Wvb, Wh2b};
        int srclds[8] = {INF_, INF_, INF_+HID, INF_, INF_+HID, HID, HID, INF_+HID};
        int col0s[8]  = {0,0,0,0,0, 0,0,INF_};
        int ncolss[8] = {INF_,INF_,INF_,INF_,INF_, HID,HID,HID};
        int dstlds[8] = {KPAD,KPAD,KPAD,KPAD,KPAD, HID,HID,HID};
        int sizes[8]  = {NMSG*KPAD, 256*KPAD,256*KPAD,256*KPAD,256*KPAD,
                         256*HID,256*HID,256*HID};
        int st = 0;
        for (int j = 0; j < 8; ++j){
            cs.src[j]=srcs[j]; cs.dst[j]=dsts[j]; cs.srcld[j]=srclds[j];
            cs.col0[j]=col0s[j]; cs.ncols[j]=ncolss[j]; cs.dstld[j]=dstlds[j];
            cs.start[j]=st; st += sizes[j];
        }
        convall_k<<<(st+255)/256, gb, 0, stream>>>(cs, st);
    }
    wcomb_k<<<512, gb, 0, stream>>>(Ur, Wz, Wv, bv, bur, bz, Urv, Wzv, bur2, bz2);
    hipMemsetAsync(zreg, 0, zbytes, stream);

    // ---- precompute: [sq | Fz | Fr | Fh] = fmess_bf16 @ Wcat^T (K=160) ----
    mm_k<0><<<dim3(NMSG/128, 16), gb, 0, stream>>>(fmessb, nullptr, Wcat, nullptr, KPAD,
        nullptr, nullptr, bq, nullptr, nullptr,
        nullptr, FZb, FRb, FHb, alpha, sq, nullptr);

    // ---- steps; step 0 skips G1+attn (h=0 -> h_agg=0 exactly) ----
    for (int step = 0; step < DEPTH; ++step){
        const bool last = (step == DEPTH-1);
        float* cf    = last ? out : nullptr;
        bf16*  cb    = last ? nullptr : hb;
        float* Snext = last ? nullptr : (S_all + (step+1)*(size_t)NMSG);
        if (step > 0){
            // G1: sk scalars from h@Wk^T (fused reduction, no matrix output)
            mm_k<1><<<dim3(NMSG/64, 4), gb, 0, stream>>>(hb, nullptr, Wkb, nullptr, HID,
                nullptr, nullptr, bk, nullptr, nullptr,
                nullptr, nullptr, nullptr, nullptr, alpha + DPH, sk, nullptr);
            attn_k<<<rgrid, gb, 0, stream>>>(bgraph, sq, sk, S_all + step*(size_t)NMSG,
                                             abias, hb, haggb);
        }
        // G2: {sumh = h_agg@Wv^T + bv ; rs = sigmoid(h_agg@Urv^T + Fr + bur2) * sumh}
        mm_k<2><<<dim3(NMSG/64, 4), gb, 0, stream>>>(haggb, nullptr, Wvb, Urv, HID,
            nullptr, FRb, bv, bur2, nullptr,
            nullptr, sumhb, rsb, nullptr, nullptr, nullptr, nullptr);
        // G3: {z = sigmoid(h_agg@Wzv^T + Fz + bz2) ; h = ((1-z)sumh + z tanh(rs@Wh2^T + Fh + bh))}
        mm_k<3><<<dim3(NMSG/64, 4), gb, 0, stream>>>(rsb, haggb, Wh2b, Wzv, HID,
            FHb, FZb, bh, bz2, sumhb,
            cf, cb, nullptr, nullptr, nullptr, nullptr, Snext);
    }
}